// Round 22
// baseline (128.609 us; speedup 1.0000x reference)
//
#include <hip/hip_runtime.h>
#include <hip/hip_bf16.h>
#include <cstdint>

#define NHEAD 16
#define DKK 64
#define BB 2
#define SS 2048
#define DMODEL 1024

typedef __attribute__((ext_vector_type(8))) short s16x8;
typedef __attribute__((ext_vector_type(4))) float f32x4;
typedef __attribute__((ext_vector_type(4))) int i32x4;

#if __has_builtin(__builtin_amdgcn_exp2f)
#define EXP2(x) __builtin_amdgcn_exp2f(x)
#else
#define EXP2(x) exp2f(x)
#endif

__device__ __forceinline__ void split1(float x, short& h, short& l) {
  __hip_bfloat16 hb = __float2bfloat16(x);
  float hf = __bfloat162float(hb);
  __hip_bfloat16 lb = __float2bfloat16(x - hf);
  h = *reinterpret_cast<short*>(&hb);
  l = *reinterpret_cast<short*>(&lb);
}

__device__ __forceinline__ short bf16s(float x) {
  __hip_bfloat16 b = __float2bfloat16(x);
  return *reinterpret_cast<short*>(&b);
}

// pack two fp32 -> two TRUNCATED bf16 in one dword (a -> low, b -> high).
__device__ __forceinline__ int pack_trunc(float a, float b) {
  unsigned ua = __builtin_bit_cast(unsigned, a);
  unsigned ub = __builtin_bit_cast(unsigned, b);
  return (int)((ub & 0xFFFF0000u) | (ua >> 16));
}

__device__ __forceinline__ void gl16(const short* g, short* l) {
  __builtin_amdgcn_global_load_lds(
      (const __attribute__((address_space(1))) void*)g,
      (__attribute__((address_space(3))) void*)l, 16, 0, 0);
}

// ---------------------------------------------------------------------------
// Weight pre-pass ONLY. w_q/w_k hi only; w_v lo -> slot 0; w_o lo -> slot 1.
// ---------------------------------------------------------------------------
__global__ __launch_bounds__(256) void prep_all(
    const float* __restrict__ w0, const float* __restrict__ w1,
    const float* __restrict__ w2, const float* __restrict__ w3,
    short* __restrict__ whi, short* __restrict__ wlo) {
  const int bid = blockIdx.x;
  const int which = bid >> 10;
  const int i = ((bid & 1023) << 8) + threadIdx.x;
  const float* src = (which == 0) ? w0 : (which == 1) ? w1 : (which == 2) ? w2 : w3;
  float4 vv = ((const float4*)src)[i];
  const size_t hoff = (size_t)which * (DMODEL * DMODEL) + (size_t)i * 4;
  if (which >= 2) {
    short4 h, l;
    split1(vv.x, h.x, l.x);
    split1(vv.y, h.y, l.y);
    split1(vv.z, h.z, l.z);
    split1(vv.w, h.w, l.w);
    *(short4*)&whi[hoff] = h;
    *(short4*)&wlo[(size_t)(which - 2) * (DMODEL * DMODEL) + (size_t)i * 4] = l;
  } else {
    short4 h;
    h.x = bf16s(vv.x); h.y = bf16s(vv.y); h.z = bf16s(vv.z); h.w = bf16s(vv.w);
    *(short4*)&whi[hoff] = h;
  }
}

// ---------------------------------------------------------------------------
// Unified QKV projection GEMM with fused A-side fp32->bf16 conversion AND
// A-loads software-pipelined ONE K-STEP AHEAD: tile t+1's global_load_dwordx4
// issue right after tile t's staging, so their latency hides under tile t's
// MFMA phase; the staging phase is pure cvt + ds_write (no vmcnt stall).
// BM=BN=128, 48 KB LDS, V = A x (Whi+Wlo) 2-MFMA.
// ---------------------------------------------------------------------------
__global__ __launch_bounds__(256) void gemm_qkv(
    const float* __restrict__ Xa, const float* __restrict__ Xb,
    const float* __restrict__ Xc, const short* __restrict__ WhiA,
    const short* __restrict__ WloA, float qscale, short* __restrict__ Qb,
    short* __restrict__ Kb, short* __restrict__ Vth) {
  __shared__ short Ah[128 * 64];
  __shared__ short Bhs[128 * 64];
  __shared__ short Bls[128 * 64];

  const int z = blockIdx.z;
  const size_t wsz = (size_t)DMODEL * DMODEL;
  const float* A = (z == 0) ? Xa : (z == 1) ? Xb : Xc;
  const short* Bhi = WhiA + (size_t)z * wsz;
  const short* Blo = WloA;  // v-lo (slot 0), used only when z==2

  const int tid = threadIdx.x;
  const int lane = tid & 63;
  const int w = tid >> 6;
  const int wm = (w >> 1) * 64;
  const int wn = (w & 1) * 64;

  // bijective XCD remap within each z-slice: 256 blocks, 32/XCD
  const int flat = blockIdx.y * 8 + blockIdx.x;
  const int f2 = (flat & 7) * 32 + (flat >> 3);
  const int n0 = (f2 & 7) * 128;
  const int m0 = (f2 >> 3) * 128;

  const int srow = lane >> 3;
  const int slot = lane & 7;
  const int gslot = slot ^ srow;  // B gl16 source swizzle

  f32x4 acc[4][4];
#pragma unroll
  for (int r = 0; r < 4; ++r)
#pragma unroll
    for (int c = 0; c < 4; ++c) acc[r][c] = (f32x4){0.f, 0.f, 0.f, 0.f};

  float4 fa0[4], fa1[4];  // prefetched A fp32 (compile-time indexed)

#define LOAD_A_REGS(K0)                                                       \
  _Pragma("unroll") for (int i = 0; i < 4; ++i) {                             \
    const int row = (w * 4 + i) * 8 + srow;                                   \
    const float* ap = &A[(size_t)(m0 + row) * DMODEL + (K0) + slot * 8];      \
    fa0[i] = *(const float4*)ap;                                              \
    fa1[i] = *(const float4*)(ap + 4);                                        \
  }

  LOAD_A_REGS(0);

  for (int k0 = 0; k0 < DMODEL; k0 += 64) {
    __syncthreads();
    // ---- B staging via gl16 (hi, + lo when z==2) ----
#pragma unroll
    for (int i = 0; i < 4; ++i) {
      const int gb = w * 4 + i;
      const int row = gb * 8 + srow;
      const size_t go = (size_t)(n0 + row) * DMODEL + k0 + gslot * 8;
      gl16(&Bhi[go], &Bhs[gb * 512]);
      if (z == 2) gl16(&Blo[go], &Bls[gb * 512]);
    }
    // ---- A staging: prefetched regs -> bf16 -> swizzled ds_write ----
#pragma unroll
    for (int i = 0; i < 4; ++i) {
      const int row = (w * 4 + i) * 8 + srow;
      s16x8 hv;
      hv[0] = bf16s(fa0[i].x); hv[1] = bf16s(fa0[i].y);
      hv[2] = bf16s(fa0[i].z); hv[3] = bf16s(fa0[i].w);
      hv[4] = bf16s(fa1[i].x); hv[5] = bf16s(fa1[i].y);
      hv[6] = bf16s(fa1[i].z); hv[7] = bf16s(fa1[i].w);
      *(s16x8*)&Ah[row * 64 + ((slot ^ (row & 7)) * 8)] = hv;
    }
    // ---- prefetch A for next K-step (latency hides under MFMA below) ----
    if (k0 + 64 < DMODEL) LOAD_A_REGS(k0 + 64);
    __syncthreads();

#pragma unroll
    for (int ks = 0; ks < 2; ++ks) {
      const int kslot = (lane >> 4) + ks * 4;
      s16x8 ah[4], bh[4], bl[4];
#pragma unroll
      for (int r = 0; r < 4; ++r) {
        const int row = wm + r * 16 + (lane & 15);
        ah[r] = *(const s16x8*)&Ah[row * 64 + (kslot ^ (row & 7)) * 8];
      }
#pragma unroll
      for (int c = 0; c < 4; ++c) {
        const int row = wn + c * 16 + (lane & 15);
        const int ssw = (kslot ^ (row & 7)) * 8;
        bh[c] = *(const s16x8*)&Bhs[row * 64 + ssw];
        if (z == 2) bl[c] = *(const s16x8*)&Bls[row * 64 + ssw];
      }
#pragma unroll
      for (int r = 0; r < 4; ++r)
#pragma unroll
        for (int c = 0; c < 4; ++c) {
          if (z == 2)
            acc[r][c] = __builtin_amdgcn_mfma_f32_16x16x32_bf16(ah[r], bl[c], acc[r][c], 0, 0, 0);
          acc[r][c] = __builtin_amdgcn_mfma_f32_16x16x32_bf16(ah[r], bh[c], acc[r][c], 0, 0, 0);
        }
    }
  }
#undef LOAD_A_REGS

  const int lrow = (lane >> 4) * 4;
  const int lcol = lane & 15;
  const float scale = (z == 0) ? qscale : 1.0f;
#pragma unroll
  for (int r = 0; r < 4; ++r)
#pragma unroll
    for (int c = 0; c < 4; ++c) {
      const int n = n0 + wn + c * 16 + lcol;
      const int h = n >> 6;
      const int dk = n & 63;
      if (z < 2) {
        short* Y = (z == 0) ? Qb : Kb;
#pragma unroll
        for (int j = 0; j < 4; ++j) {
          const int m = m0 + wm + r * 16 + lrow + j;
          const size_t off =
              (((size_t)((m >> 11) * NHEAD + h)) * SS + (m & (SS - 1))) * DKK + dk;
          Y[off] = bf16s(acc[r][c][j] * scale);
        }
      } else {
        const int mb = m0 + wm + r * 16 + lrow;
        short4 h4;
        h4.x = bf16s(acc[r][c][0]);
        h4.y = bf16s(acc[r][c][1]);
        h4.z = bf16s(acc[r][c][2]);
        h4.w = bf16s(acc[r][c][3]);
        const size_t off =
            (((size_t)((mb >> 11) * NHEAD + h)) * DKK + dk) * SS + (mb & (SS - 1));
        *(short4*)&Vth[off] = h4;
      }
    }
}

// ---------------------------------------------------------------------------
// O projection: full split-bf16 (3 MFMA), fp32 out + bias. (o-lo = slot 1)
// ---------------------------------------------------------------------------
__global__ __launch_bounds__(256) void gemm_split_o(
    const short* __restrict__ Ahi, const short* __restrict__ Alo,
    const short* __restrict__ Bhi, const short* __restrict__ Blo,
    const float* __restrict__ bias, float* __restrict__ Yf) {
  __shared__ short Ah[128 * 64];
  __shared__ short Al[128 * 64];
  __shared__ short Bh[64 * 64];
  __shared__ short Bl[64 * 64];

  const int tid = threadIdx.x;
  const int lane = tid & 63;
  const int w = tid >> 6;
  const int wm = (w >> 1) * 64;
  const int wn = (w & 1) * 32;

  const int flat = blockIdx.y * 16 + blockIdx.x;
  const int f2 = (flat & 7) * 64 + (flat >> 3);
  const int n0 = (f2 & 15) * 64;
  const int m0 = (f2 >> 4) * 128;

  const int srow = lane >> 3;
  const int gslot = (lane & 7) ^ srow;

  f32x4 acc[4][2];
#pragma unroll
  for (int r = 0; r < 4; ++r)
#pragma unroll
    for (int c = 0; c < 2; ++c) acc[r][c] = (f32x4){0.f, 0.f, 0.f, 0.f};

  for (int k0 = 0; k0 < DMODEL; k0 += 64) {
    __syncthreads();
#pragma unroll
    for (int i = 0; i < 4; ++i) {
      const int gb = w * 4 + i;
      const int row = gb * 8 + srow;
      const size_t ga = (size_t)(m0 + row) * DMODEL + k0 + gslot * 8;
      gl16(&Ahi[ga], &Ah[gb * 512]);
      gl16(&Alo[ga], &Al[gb * 512]);
    }
#pragma unroll
    for (int i = 0; i < 2; ++i) {
      const int gb = w * 2 + i;
      const int row = gb * 8 + srow;
      const size_t gbo = (size_t)(n0 + row) * DMODEL + k0 + gslot * 8;
      gl16(&Bhi[gbo], &Bh[gb * 512]);
      gl16(&Blo[gbo], &Bl[gb * 512]);
    }
    __syncthreads();

#pragma unroll
    for (int ks = 0; ks < 2; ++ks) {
      const int kslot = (lane >> 4) + ks * 4;
      s16x8 ah[4], al[4], bh[2], bl[2];
#pragma unroll
      for (int r = 0; r < 4; ++r) {
        const int row = wm + r * 16 + (lane & 15);
        const int ssw = (kslot ^ (row & 7)) * 8;
        ah[r] = *(const s16x8*)&Ah[row * 64 + ssw];
        al[r] = *(const s16x8*)&Al[row * 64 + ssw];
      }
#pragma unroll
      for (int c = 0; c < 2; ++c) {
        const int row = wn + c * 16 + (lane & 15);
        const int ssw = (kslot ^ (row & 7)) * 8;
        bh[c] = *(const s16x8*)&Bh[row * 64 + ssw];
        bl[c] = *(const s16x8*)&Bl[row * 64 + ssw];
      }
#pragma unroll
      for (int r = 0; r < 4; ++r)
#pragma unroll
        for (int c = 0; c < 2; ++c) {
          acc[r][c] = __builtin_amdgcn_mfma_f32_16x16x32_bf16(al[r], bh[c], acc[r][c], 0, 0, 0);
          acc[r][c] = __builtin_amdgcn_mfma_f32_16x16x32_bf16(ah[r], bl[c], acc[r][c], 0, 0, 0);
          acc[r][c] = __builtin_amdgcn_mfma_f32_16x16x32_bf16(ah[r], bh[c], acc[r][c], 0, 0, 0);
        }
    }
  }

  const int lrow = (lane >> 4) * 4;
  const int lcol = lane & 15;
#pragma unroll
  for (int r = 0; r < 4; ++r)
#pragma unroll
    for (int c = 0; c < 2; ++c) {
      const int n = n0 + wn + c * 16 + lcol;
      const float bv = bias[n];
#pragma unroll
      for (int j = 0; j < 4; ++j) {
        const int m = m0 + wm + r * 16 + lrow + j;
        Yf[(size_t)m * DMODEL + n] = acc[r][c][j] + bv;
      }
    }
}

// ---------------------------------------------------------------------------
// Flash attention v13 (byte-identical to round 19/21).
// ---------------------------------------------------------------------------
__global__ __launch_bounds__(512) void attn_mfma(
    const short* __restrict__ Qh_g, const short* __restrict__ Kh_g,
    const short* __restrict__ Vh_g,
    short* __restrict__ AOh, short* __restrict__ AOl) {
  __shared__ short lds[2][2][2][64 * 64];
  __shared__ float Lsh[256];

  const int tid = threadIdx.x;
  const int grp = tid >> 8;
  const int gtid = tid & 255;
  const int lane = tid & 63;
  const int w = gtid >> 6;
  const int col = lane & 15;
  const int g = lane >> 4;

  const int flat = blockIdx.y * gridDim.x + blockIdx.x;
  const int remap = (flat & 7) * 32 + (flat >> 3);
  const int bh = remap >> 3;
  const int q0 = (remap & 7) * 256;

  const size_t hb = (size_t)bh * SS * DKK;

  const int row0 = gtid >> 3, row1 = row0 + 32;
  const int slot = gtid & 7;
  const int kds0 = row0 * 64 + ((slot ^ (row0 & 7)) * 8);
  const int kds1 = row1 * 64 + ((slot ^ (row1 & 7)) * 8);
  const int baseA = (slot >> 2) * 8 + ((2 * slot) & 3) * 2 + ((slot >> 1) & 1);
  const int baseB = (slot >> 2) * 8 + ((2 * slot + 1) & 3) * 2 + ((slot >> 1) & 1);
  const int sw0 = (row0 & 7) << 1, sw1 = (row1 & 7) << 1;
  const int vA0 = row0 * 64 + (baseA ^ sw0) * 4;
  const int vB0 = row0 * 64 + (baseB ^ sw0) * 4;
  const int vA1 = row1 * 64 + (baseA ^ sw1) * 4;
  const int vB1 = row1 * 64 + (baseB ^ sw1) * 4;

  s16x8 qbh[4][2];
#pragma unroll
  for (int qq = 0; qq < 4; ++qq)
#pragma unroll
    for (int ks = 0; ks < 2; ++ks) {
      const size_t off =
          hb + (size_t)(q0 + w * 64 + qq * 16 + col) * DKK + g * 8 + ks * 32;
      qbh[qq][ks] = *(const s16x8*)&Qh_g[off];
    }

  f32x4 oacc[4][4];
  f32x4 lacc[4];
#pragma unroll
  for (int qq = 0; qq < 4; ++qq) {
#pragma unroll
    for (int mt = 0; mt < 4; ++mt) oacc[qq][mt] = (f32x4){0.f, 0.f, 0.f, 0.f};
    lacc[qq] = (f32x4){0.f, 0.f, 0.f, 0.f};
  }
  const float SOFF = -12.0f;
  const short ONE = 0x3F80;
  const s16x8 vones = (s16x8){ONE, ONE, ONE, ONE, ONE, ONE, ONE, ONE};

  s16x8 nkh0, nvh0, nkh1, nvh1;

#define LOAD_TILE(KV0)                                                        \
  {                                                                           \
    const int kv0_ = (KV0);                                                   \
    nkh0 = *(const s16x8*)&Kh_g[hb + (size_t)(kv0_ + row0) * DKK + slot * 8]; \
    nkh1 = *(const s16x8*)&Kh_g[hb + (size_t)(kv0_ + row1) * DKK + slot * 8]; \
    nvh0 = *(const s16x8*)&Vh_g[hb + (size_t)row0 * SS + kv0_ + slot * 8];    \
    nvh1 = *(const s16x8*)&Vh_g[hb + (size_t)row1 * SS + kv0_ + slot * 8];    \
  }

#define WRITE_TILE(BUF)                                                       \
  {                                                                           \
    *(s16x8*)&lds[grp][BUF][0][kds0] = nkh0;                                  \
    *(s16x8*)&lds[grp][BUF][0][kds1] = nkh1;                                  \
    *(short4*)&lds[grp][BUF][1][vA0] = (short4){nvh0[0], nvh0[1], nvh0[2], nvh0[3]}; \
    *(short4*)&lds[grp][BUF][1][vB0] = (short4){nvh0[4], nvh0[5], nvh0[6], nvh0[7]}; \
    *(short4*)&lds[grp][BUF][1][vA1] = (short4){nvh1[0], nvh1[1], nvh1[2], nvh1[3]}; \
    *(short4*)&lds[grp][BUF][1][vB1] = (short4){nvh1[4], nvh1[5], nvh1[6], nvh1[7]}; \
  }

#define COMPUTE(BUF)                                                          \
  {                                                                           \
    f32x4 sacc[4][4];                                                         \
    _Pragma("unroll") for (int qq = 0; qq < 4; ++qq)                          \
        _Pragma("unroll") for (int mt = 0; mt < 4; ++mt)                      \
            sacc[qq][mt] = (f32x4){SOFF, SOFF, SOFF, SOFF};                   \
    __builtin_amdgcn_s_setprio(1);                                            \
    _Pragma("unroll") for (int mt = 0; mt < 4; ++mt) {                        \
      const int ar = mt * 16 + col;                                           \
      _Pragma("unroll") for (int ks = 0; ks < 2; ++ks) {                      \
        const int as = ar * 64 + (((g + 4 * ks) ^ (ar & 7)) * 8);             \
        const s16x8 kh = *(const s16x8*)&lds[grp][BUF][0][as];                \
        _Pragma("unroll") for (int qq = 0; qq < 4; ++qq)                      \
            sacc[qq][mt] = __builtin_amdgcn_mfma_f32_16x16x32_bf16(           \
                kh, qbh[qq][ks], sacc[qq][mt], 0, 0, 0);                      \
      }                                                                       \
    }                                                                         \
    __builtin_amdgcn_s_setprio(0);                                            \
    _Pragma("unroll") for (int qq = 0; qq < 4; ++qq)                          \
        _Pragma("unroll") for (int mt = 0; mt < 4; ++mt) {                    \
      sacc[qq][mt][0] = EXP2(sacc[qq][mt][0]);                                \
      sacc[qq][mt][1] = EXP2(sacc[qq][mt][1]);                                \
      sacc[qq][mt][2] = EXP2(sacc[qq][mt][2]);                                \
      sacc[qq][mt][3] = EXP2(sacc[qq][mt][3]);                                \
    }                                                                         \
    s16x8 pbh[4][2];                                                          \
    _Pragma("unroll") for (int qq = 0; qq < 4; ++qq)                          \
        _Pragma("unroll") for (int ks = 0; ks < 2; ++ks) {                    \
      i32x4 pw;                                                               \
      _Pragma("unroll") for (int d = 0; d < 4; ++d) {                         \
        const int mtd = 2 * ks + (d >> 1);                                    \
        const int j0 = (d & 1) * 2;                                           \
        pw[d] = pack_trunc(sacc[qq][mtd][j0], sacc[qq][mtd][j0 + 1]);         \
      }                                                                       \
      pbh[qq][ks] = __builtin_bit_cast(s16x8, pw);                            \
    }                                                                         \
    __builtin_amdgcn_s_setprio(1);                                            \
    _Pragma("unroll") for (int qq = 0; qq < 4; ++qq) {                        \
      lacc[qq] = __builtin_amdgcn_mfma_f32_16x16x32_bf16(                     \
          vones, pbh[qq][0], lacc[qq], 0, 0, 0);                              \
      lacc[qq] = __builtin_amdgcn_mfma_f32_16x16x32_bf16(                     \
          vones, pbh[qq][1], lacc[qq], 0, 0, 0);                              \
    }                                                                         \
    _Pragma("unroll") for (int mt = 0; mt < 4; ++mt) {                        \
      const int row = mt * 16 + col;                                          \
      const int sw = (row & 7) << 1;                                          \
      _Pragma("unroll") for (int ks = 0; ks < 2; ++ks) {                      \
        const int c0 = (8 * ks + 2 * g) ^ sw;                                 \
        const s16x8 vh = *(const s16x8*)&lds[grp][BUF][1][row * 64 + c0 * 4]; \
        _Pragma("unroll") for (int qq = 0; qq < 4; ++qq)                      \
            oacc[qq][mt] = __builtin_amdgcn_mfma_f32_16x16x32_bf16(           \
                vh, pbh[qq][ks], oacc[qq][mt], 0, 0, 0);                      \
      }                                                                       \
    }                                                                         \
    __builtin_amdgcn_s_setprio(0);                                            \
  }

  LOAD_TILE(64 * grp);
  WRITE_TILE(0);
  __syncthreads();

  for (int i = 0; i < 16; i += 2) {
    if (i + 1 < 16) LOAD_TILE(128 * (i + 1) + 64 * grp);
    COMPUTE(0);
    if (i + 1 < 16) WRITE_TILE(1);
    __syncthreads();
    if (i + 2 < 16) LOAD_TILE(128 * (i + 2) + 64 * grp);
    COMPUTE(1);
    if (i + 2 < 16) WRITE_TILE(0);
    __syncthreads();
  }

  // ---- linear merge: group 1 -> LDS, group 0 adds, normalizes, writes ----
  float* fbuf = (float*)&lds[0][0][0][0];
  if (grp == 1) {
#pragma unroll
    for (int qq = 0; qq < 4; ++qq) {
      Lsh[(w * 4 + qq) * 16 + col] = lacc[qq][0];
#pragma unroll
      for (int mt = 0; mt < 4; ++mt) {
        const int idx = ((w * 4 + qq) * 4 + mt) * 256 + lane * 4;
        *(float4*)&fbuf[idx] = make_float4(oacc[qq][mt][0], oacc[qq][mt][1],
                                           oacc[qq][mt][2], oacc[qq][mt][3]);
      }
    }
  }
  __syncthreads();
  if (grp == 0) {
    const int b = bh >> 4;
    const int h = bh & 15;
#pragma unroll
    for (int qq = 0; qq < 4; ++qq) {
      const float l1 = Lsh[(w * 4 + qq) * 16 + col];
      const float inv = 1.0f / (lacc[qq][0] + l1);
      const int q = q0 + w * 64 + qq * 16 + col;
      const size_t rb = ((size_t)b * SS + q) * DMODEL + h * DKK;
#pragma unroll
      for (int mt = 0; mt < 4; ++mt) {
        const int idx = ((w * 4 + qq) * 4 + mt) * 256 + lane * 4;
        const float4 o1 = *(const float4*)&fbuf[idx];
        short4 h4, l4;
        split1((oacc[qq][mt][0] + o1.x) * inv, h4.x, l4.x);
        split1((oacc[qq][mt][1] + o1.y) * inv, h4.y, l4.y);
        split1((oacc[qq][mt][2] + o1.z) * inv, h4.z, l4.z);
        split1((oacc[qq][mt][3] + o1.w) * inv, h4.w, l4.w);
        *(short4*)&AOh[rb + mt * 16 + g * 4] = h4;
        *(short4*)&AOl[rb + mt * 16 + g * 4] = l4;
      }
    }
  }
#undef LOAD_TILE
#undef WRITE_TILE
#undef COMPUTE
}

extern "C" void kernel_launch(void* const* d_in, const int* in_sizes, int n_in,
                              void* d_out, int out_size, void* d_ws,
                              size_t ws_size, hipStream_t stream) {
  const float* query = (const float*)d_in[0];
  const float* key   = (const float*)d_in[1];
  const float* value = (const float*)d_in[2];
  const float* w_q   = (const float*)d_in[3];
  const float* w_k   = (const float*)d_in[4];
  const float* w_v   = (const float*)d_in[5];
  const float* w_o   = (const float*)d_in[6];
  const float* b_o   = (const float*)d_in[7];
  float* out = (float*)d_out;

  const size_t per = (size_t)BB * NHEAD * SS * DKK;   // 4,194,304 elements
  const size_t wsz = (size_t)DMODEL * DMODEL;
  short* Qbh = (short*)d_ws;     // bf16 Q (pre-scaled)
  short* Kbh = Qbh + per;        // bf16 K
  short* Vth = Kbh + per;        // bf16 V^T
  short* AOh = Vth + per;        // attention out hi
  short* AOl = AOh + per;        // attention out lo
  short* WhiA = AOl + per;       // 4 weights hi (q,k,v,o)
  short* WloA = WhiA + 4 * wsz;  // 2 compact lo slots (v, o)

  const float QSCALE = 0.125f * 1.4426950408889634f;  // 1/sqrt(64)*log2(e)
  dim3 blk(256);

  prep_all<<<4096, blk, 0, stream>>>(w_q, w_k, w_v, w_o, WhiA, WloA);

  dim3 gqkv(DMODEL / 128, (BB * SS) / 128, 3);  // (8, 32, 3) = 768 blocks
  gemm_qkv<<<gqkv, blk, 0, stream>>>(query, key, value, WhiA, WloA, QSCALE,
                                     Qbh, Kbh, Vth);

  dim3 gattn(SS / 256, BB * NHEAD);  // (8, 32) = 256 blocks, 512 thr
  attn_mfma<<<gattn, dim3(512), 0, stream>>>(Qbh, Kbh, Vth, AOh, AOl);

  dim3 ggemm(DMODEL / 64, (BB * SS) / 128);  // (16, 32)
  gemm_split_o<<<ggemm, blk, 0, stream>>>(AOh, AOl, WhiA + 3 * wsz,
                                          WloA + 1 * wsz, b_o, out);
}

// Round 23
// 118.329 us; speedup vs baseline: 1.0869x; 1.0869x over previous
//
#include <hip/hip_runtime.h>
#include <hip/hip_bf16.h>
#include <cstdint>

#define NHEAD 16
#define DKK 64
#define BB 2
#define SS 2048
#define DMODEL 1024

typedef __attribute__((ext_vector_type(8))) short s16x8;
typedef __attribute__((ext_vector_type(4))) float f32x4;
typedef __attribute__((ext_vector_type(4))) int i32x4;

#if __has_builtin(__builtin_amdgcn_exp2f)
#define EXP2(x) __builtin_amdgcn_exp2f(x)
#else
#define EXP2(x) exp2f(x)
#endif

__device__ __forceinline__ void split1(float x, short& h, short& l) {
  __hip_bfloat16 hb = __float2bfloat16(x);
  float hf = __bfloat162float(hb);
  __hip_bfloat16 lb = __float2bfloat16(x - hf);
  h = *reinterpret_cast<short*>(&hb);
  l = *reinterpret_cast<short*>(&lb);
}

__device__ __forceinline__ short bf16s(float x) {
  __hip_bfloat16 b = __float2bfloat16(x);
  return *reinterpret_cast<short*>(&b);
}

// pack two fp32 -> two TRUNCATED bf16 in one dword (a -> low, b -> high).
__device__ __forceinline__ int pack_trunc(float a, float b) {
  unsigned ua = __builtin_bit_cast(unsigned, a);
  unsigned ub = __builtin_bit_cast(unsigned, b);
  return (int)((ub & 0xFFFF0000u) | (ua >> 16));
}

__device__ __forceinline__ void gl16(const short* g, short* l) {
  __builtin_amdgcn_global_load_lds(
      (const __attribute__((address_space(1))) void*)g,
      (__attribute__((address_space(3))) void*)l, 16, 0, 0);
}

// ---------------------------------------------------------------------------
// Weight pre-pass ONLY. w_q/w_k hi only; w_v lo -> slot 0; w_o lo -> slot 1.
// ---------------------------------------------------------------------------
__global__ __launch_bounds__(256) void prep_all(
    const float* __restrict__ w0, const float* __restrict__ w1,
    const float* __restrict__ w2, const float* __restrict__ w3,
    short* __restrict__ whi, short* __restrict__ wlo) {
  const int bid = blockIdx.x;
  const int which = bid >> 10;
  const int i = ((bid & 1023) << 8) + threadIdx.x;
  const float* src = (which == 0) ? w0 : (which == 1) ? w1 : (which == 2) ? w2 : w3;
  float4 vv = ((const float4*)src)[i];
  const size_t hoff = (size_t)which * (DMODEL * DMODEL) + (size_t)i * 4;
  if (which >= 2) {
    short4 h, l;
    split1(vv.x, h.x, l.x);
    split1(vv.y, h.y, l.y);
    split1(vv.z, h.z, l.z);
    split1(vv.w, h.w, l.w);
    *(short4*)&whi[hoff] = h;
    *(short4*)&wlo[(size_t)(which - 2) * (DMODEL * DMODEL) + (size_t)i * 4] = l;
  } else {
    short4 h;
    h.x = bf16s(vv.x); h.y = bf16s(vv.y); h.z = bf16s(vv.z); h.w = bf16s(vv.w);
    *(short4*)&whi[hoff] = h;
  }
}

// ---------------------------------------------------------------------------
// Unified QKV projection GEMM, fused A-side fp32->bf16 conversion (R21) with
// REORDERED staging: A fp32 loads issue FIRST (oldest VMEM ops), B gl16s
// after. The cvt's wait for A data then leaves the B DMA loads in flight
// (vmcnt in-order semantics); they drain only at the barrier, overlapping
// their latency with the A-wait + cvt + ds_write work.
// BM=BN=128, 48 KB LDS, V = A x (Whi+Wlo) 2-MFMA.
// ---------------------------------------------------------------------------
__global__ __launch_bounds__(256) void gemm_qkv(
    const float* __restrict__ Xa, const float* __restrict__ Xb,
    const float* __restrict__ Xc, const short* __restrict__ WhiA,
    const short* __restrict__ WloA, float qscale, short* __restrict__ Qb,
    short* __restrict__ Kb, short* __restrict__ Vth) {
  __shared__ short Ah[128 * 64];
  __shared__ short Bhs[128 * 64];
  __shared__ short Bls[128 * 64];

  const int z = blockIdx.z;
  const size_t wsz = (size_t)DMODEL * DMODEL;
  const float* A = (z == 0) ? Xa : (z == 1) ? Xb : Xc;
  const short* Bhi = WhiA + (size_t)z * wsz;
  const short* Blo = WloA;  // v-lo (slot 0), used only when z==2

  const int tid = threadIdx.x;
  const int lane = tid & 63;
  const int w = tid >> 6;
  const int wm = (w >> 1) * 64;
  const int wn = (w & 1) * 64;

  // bijective XCD remap within each z-slice: 256 blocks, 32/XCD
  const int flat = blockIdx.y * 8 + blockIdx.x;
  const int f2 = (flat & 7) * 32 + (flat >> 3);
  const int n0 = (f2 & 7) * 128;
  const int m0 = (f2 >> 3) * 128;

  const int srow = lane >> 3;
  const int slot = lane & 7;
  const int gslot = slot ^ srow;  // B gl16 source swizzle

  f32x4 acc[4][4];
#pragma unroll
  for (int r = 0; r < 4; ++r)
#pragma unroll
    for (int c = 0; c < 4; ++c) acc[r][c] = (f32x4){0.f, 0.f, 0.f, 0.f};

  for (int k0 = 0; k0 < DMODEL; k0 += 64) {
    __syncthreads();
    // ---- A fp32 loads FIRST (oldest VMEM ops) ----
    float4 fa0[4], fa1[4];
#pragma unroll
    for (int i = 0; i < 4; ++i) {
      const int row = (w * 4 + i) * 8 + srow;
      const float* ap = &A[(size_t)(m0 + row) * DMODEL + k0 + slot * 8];
      fa0[i] = *(const float4*)ap;
      fa1[i] = *(const float4*)(ap + 4);
    }
    // ---- B staging via gl16 (newer; stays in flight during A cvt) ----
#pragma unroll
    for (int i = 0; i < 4; ++i) {
      const int gb = w * 4 + i;
      const int row = gb * 8 + srow;
      const size_t go = (size_t)(n0 + row) * DMODEL + k0 + gslot * 8;
      gl16(&Bhi[go], &Bhs[gb * 512]);
      if (z == 2) gl16(&Blo[go], &Bls[gb * 512]);
    }
    // ---- A: cvt + swizzled ds_write (waits only on the A loads) ----
#pragma unroll
    for (int i = 0; i < 4; ++i) {
      const int row = (w * 4 + i) * 8 + srow;
      s16x8 hv;
      hv[0] = bf16s(fa0[i].x); hv[1] = bf16s(fa0[i].y);
      hv[2] = bf16s(fa0[i].z); hv[3] = bf16s(fa0[i].w);
      hv[4] = bf16s(fa1[i].x); hv[5] = bf16s(fa1[i].y);
      hv[6] = bf16s(fa1[i].z); hv[7] = bf16s(fa1[i].w);
      *(s16x8*)&Ah[row * 64 + ((slot ^ (row & 7)) * 8)] = hv;
    }
    __syncthreads();

#pragma unroll
    for (int ks = 0; ks < 2; ++ks) {
      const int kslot = (lane >> 4) + ks * 4;
      s16x8 ah[4], bh[4], bl[4];
#pragma unroll
      for (int r = 0; r < 4; ++r) {
        const int row = wm + r * 16 + (lane & 15);
        ah[r] = *(const s16x8*)&Ah[row * 64 + (kslot ^ (row & 7)) * 8];
      }
#pragma unroll
      for (int c = 0; c < 4; ++c) {
        const int row = wn + c * 16 + (lane & 15);
        const int ssw = (kslot ^ (row & 7)) * 8;
        bh[c] = *(const s16x8*)&Bhs[row * 64 + ssw];
        if (z == 2) bl[c] = *(const s16x8*)&Bls[row * 64 + ssw];
      }
#pragma unroll
      for (int r = 0; r < 4; ++r)
#pragma unroll
        for (int c = 0; c < 4; ++c) {
          if (z == 2)
            acc[r][c] = __builtin_amdgcn_mfma_f32_16x16x32_bf16(ah[r], bl[c], acc[r][c], 0, 0, 0);
          acc[r][c] = __builtin_amdgcn_mfma_f32_16x16x32_bf16(ah[r], bh[c], acc[r][c], 0, 0, 0);
        }
    }
  }

  const int lrow = (lane >> 4) * 4;
  const int lcol = lane & 15;
  const float scale = (z == 0) ? qscale : 1.0f;
#pragma unroll
  for (int r = 0; r < 4; ++r)
#pragma unroll
    for (int c = 0; c < 4; ++c) {
      const int n = n0 + wn + c * 16 + lcol;
      const int h = n >> 6;
      const int dk = n & 63;
      if (z < 2) {
        short* Y = (z == 0) ? Qb : Kb;
#pragma unroll
        for (int j = 0; j < 4; ++j) {
          const int m = m0 + wm + r * 16 + lrow + j;
          const size_t off =
              (((size_t)((m >> 11) * NHEAD + h)) * SS + (m & (SS - 1))) * DKK + dk;
          Y[off] = bf16s(acc[r][c][j] * scale);
        }
      } else {
        const int mb = m0 + wm + r * 16 + lrow;
        short4 h4;
        h4.x = bf16s(acc[r][c][0]);
        h4.y = bf16s(acc[r][c][1]);
        h4.z = bf16s(acc[r][c][2]);
        h4.w = bf16s(acc[r][c][3]);
        const size_t off =
            (((size_t)((mb >> 11) * NHEAD + h)) * DKK + dk) * SS + (mb & (SS - 1));
        *(short4*)&Vth[off] = h4;
      }
    }
}

// ---------------------------------------------------------------------------
// O projection: full split-bf16 (3 MFMA), fp32 out + bias. (o-lo = slot 1)
// ---------------------------------------------------------------------------
__global__ __launch_bounds__(256) void gemm_split_o(
    const short* __restrict__ Ahi, const short* __restrict__ Alo,
    const short* __restrict__ Bhi, const short* __restrict__ Blo,
    const float* __restrict__ bias, float* __restrict__ Yf) {
  __shared__ short Ah[128 * 64];
  __shared__ short Al[128 * 64];
  __shared__ short Bh[64 * 64];
  __shared__ short Bl[64 * 64];

  const int tid = threadIdx.x;
  const int lane = tid & 63;
  const int w = tid >> 6;
  const int wm = (w >> 1) * 64;
  const int wn = (w & 1) * 32;

  const int flat = blockIdx.y * 16 + blockIdx.x;
  const int f2 = (flat & 7) * 64 + (flat >> 3);
  const int n0 = (f2 & 15) * 64;
  const int m0 = (f2 >> 4) * 128;

  const int srow = lane >> 3;
  const int gslot = (lane & 7) ^ srow;

  f32x4 acc[4][2];
#pragma unroll
  for (int r = 0; r < 4; ++r)
#pragma unroll
    for (int c = 0; c < 2; ++c) acc[r][c] = (f32x4){0.f, 0.f, 0.f, 0.f};

  for (int k0 = 0; k0 < DMODEL; k0 += 64) {
    __syncthreads();
#pragma unroll
    for (int i = 0; i < 4; ++i) {
      const int gb = w * 4 + i;
      const int row = gb * 8 + srow;
      const size_t ga = (size_t)(m0 + row) * DMODEL + k0 + gslot * 8;
      gl16(&Ahi[ga], &Ah[gb * 512]);
      gl16(&Alo[ga], &Al[gb * 512]);
    }
#pragma unroll
    for (int i = 0; i < 2; ++i) {
      const int gb = w * 2 + i;
      const int row = gb * 8 + srow;
      const size_t gbo = (size_t)(n0 + row) * DMODEL + k0 + gslot * 8;
      gl16(&Bhi[gbo], &Bh[gb * 512]);
      gl16(&Blo[gbo], &Bl[gb * 512]);
    }
    __syncthreads();

#pragma unroll
    for (int ks = 0; ks < 2; ++ks) {
      const int kslot = (lane >> 4) + ks * 4;
      s16x8 ah[4], al[4], bh[2], bl[2];
#pragma unroll
      for (int r = 0; r < 4; ++r) {
        const int row = wm + r * 16 + (lane & 15);
        const int ssw = (kslot ^ (row & 7)) * 8;
        ah[r] = *(const s16x8*)&Ah[row * 64 + ssw];
        al[r] = *(const s16x8*)&Al[row * 64 + ssw];
      }
#pragma unroll
      for (int c = 0; c < 2; ++c) {
        const int row = wn + c * 16 + (lane & 15);
        const int ssw = (kslot ^ (row & 7)) * 8;
        bh[c] = *(const s16x8*)&Bh[row * 64 + ssw];
        bl[c] = *(const s16x8*)&Bl[row * 64 + ssw];
      }
#pragma unroll
      for (int r = 0; r < 4; ++r)
#pragma unroll
        for (int c = 0; c < 2; ++c) {
          acc[r][c] = __builtin_amdgcn_mfma_f32_16x16x32_bf16(al[r], bh[c], acc[r][c], 0, 0, 0);
          acc[r][c] = __builtin_amdgcn_mfma_f32_16x16x32_bf16(ah[r], bl[c], acc[r][c], 0, 0, 0);
          acc[r][c] = __builtin_amdgcn_mfma_f32_16x16x32_bf16(ah[r], bh[c], acc[r][c], 0, 0, 0);
        }
    }
  }

  const int lrow = (lane >> 4) * 4;
  const int lcol = lane & 15;
#pragma unroll
  for (int r = 0; r < 4; ++r)
#pragma unroll
    for (int c = 0; c < 2; ++c) {
      const int n = n0 + wn + c * 16 + lcol;
      const float bv = bias[n];
#pragma unroll
      for (int j = 0; j < 4; ++j) {
        const int m = m0 + wm + r * 16 + lrow + j;
        Yf[(size_t)m * DMODEL + n] = acc[r][c][j] + bv;
      }
    }
}

// ---------------------------------------------------------------------------
// Flash attention v13 (byte-identical to rounds 19/21).
// ---------------------------------------------------------------------------
__global__ __launch_bounds__(512) void attn_mfma(
    const short* __restrict__ Qh_g, const short* __restrict__ Kh_g,
    const short* __restrict__ Vh_g,
    short* __restrict__ AOh, short* __restrict__ AOl) {
  __shared__ short lds[2][2][2][64 * 64];
  __shared__ float Lsh[256];

  const int tid = threadIdx.x;
  const int grp = tid >> 8;
  const int gtid = tid & 255;
  const int lane = tid & 63;
  const int w = gtid >> 6;
  const int col = lane & 15;
  const int g = lane >> 4;

  const int flat = blockIdx.y * gridDim.x + blockIdx.x;
  const int remap = (flat & 7) * 32 + (flat >> 3);
  const int bh = remap >> 3;
  const int q0 = (remap & 7) * 256;

  const size_t hb = (size_t)bh * SS * DKK;

  const int row0 = gtid >> 3, row1 = row0 + 32;
  const int slot = gtid & 7;
  const int kds0 = row0 * 64 + ((slot ^ (row0 & 7)) * 8);
  const int kds1 = row1 * 64 + ((slot ^ (row1 & 7)) * 8);
  const int baseA = (slot >> 2) * 8 + ((2 * slot) & 3) * 2 + ((slot >> 1) & 1);
  const int baseB = (slot >> 2) * 8 + ((2 * slot + 1) & 3) * 2 + ((slot >> 1) & 1);
  const int sw0 = (row0 & 7) << 1, sw1 = (row1 & 7) << 1;
  const int vA0 = row0 * 64 + (baseA ^ sw0) * 4;
  const int vB0 = row0 * 64 + (baseB ^ sw0) * 4;
  const int vA1 = row1 * 64 + (baseA ^ sw1) * 4;
  const int vB1 = row1 * 64 + (baseB ^ sw1) * 4;

  s16x8 qbh[4][2];
#pragma unroll
  for (int qq = 0; qq < 4; ++qq)
#pragma unroll
    for (int ks = 0; ks < 2; ++ks) {
      const size_t off =
          hb + (size_t)(q0 + w * 64 + qq * 16 + col) * DKK + g * 8 + ks * 32;
      qbh[qq][ks] = *(const s16x8*)&Qh_g[off];
    }

  f32x4 oacc[4][4];
  f32x4 lacc[4];
#pragma unroll
  for (int qq = 0; qq < 4; ++qq) {
#pragma unroll
    for (int mt = 0; mt < 4; ++mt) oacc[qq][mt] = (f32x4){0.f, 0.f, 0.f, 0.f};
    lacc[qq] = (f32x4){0.f, 0.f, 0.f, 0.f};
  }
  const float SOFF = -12.0f;
  const short ONE = 0x3F80;
  const s16x8 vones = (s16x8){ONE, ONE, ONE, ONE, ONE, ONE, ONE, ONE};

  s16x8 nkh0, nvh0, nkh1, nvh1;

#define LOAD_TILE(KV0)                                                        \
  {                                                                           \
    const int kv0_ = (KV0);                                                   \
    nkh0 = *(const s16x8*)&Kh_g[hb + (size_t)(kv0_ + row0) * DKK + slot * 8]; \
    nkh1 = *(const s16x8*)&Kh_g[hb + (size_t)(kv0_ + row1) * DKK + slot * 8]; \
    nvh0 = *(const s16x8*)&Vh_g[hb + (size_t)row0 * SS + kv0_ + slot * 8];    \
    nvh1 = *(const s16x8*)&Vh_g[hb + (size_t)row1 * SS + kv0_ + slot * 8];    \
  }

#define WRITE_TILE(BUF)                                                       \
  {                                                                           \
    *(s16x8*)&lds[grp][BUF][0][kds0] = nkh0;                                  \
    *(s16x8*)&lds[grp][BUF][0][kds1] = nkh1;                                  \
    *(short4*)&lds[grp][BUF][1][vA0] = (short4){nvh0[0], nvh0[1], nvh0[2], nvh0[3]}; \
    *(short4*)&lds[grp][BUF][1][vB0] = (short4){nvh0[4], nvh0[5], nvh0[6], nvh0[7]}; \
    *(short4*)&lds[grp][BUF][1][vA1] = (short4){nvh1[0], nvh1[1], nvh1[2], nvh1[3]}; \
    *(short4*)&lds[grp][BUF][1][vB1] = (short4){nvh1[4], nvh1[5], nvh1[6], nvh1[7]}; \
  }

#define COMPUTE(BUF)                                                          \
  {                                                                           \
    f32x4 sacc[4][4];                                                         \
    _Pragma("unroll") for (int qq = 0; qq < 4; ++qq)                          \
        _Pragma("unroll") for (int mt = 0; mt < 4; ++mt)                      \
            sacc[qq][mt] = (f32x4){SOFF, SOFF, SOFF, SOFF};                   \
    __builtin_amdgcn_s_setprio(1);                                            \
    _Pragma("unroll") for (int mt = 0; mt < 4; ++mt) {                        \
      const int ar = mt * 16 + col;                                           \
      _Pragma("unroll") for (int ks = 0; ks < 2; ++ks) {                      \
        const int as = ar * 64 + (((g + 4 * ks) ^ (ar & 7)) * 8);             \
        const s16x8 kh = *(const s16x8*)&lds[grp][BUF][0][as];                \
        _Pragma("unroll") for (int qq = 0; qq < 4; ++qq)                      \
            sacc[qq][mt] = __builtin_amdgcn_mfma_f32_16x16x32_bf16(           \
                kh, qbh[qq][ks], sacc[qq][mt], 0, 0, 0);                      \
      }                                                                       \
    }                                                                         \
    __builtin_amdgcn_s_setprio(0);                                            \
    _Pragma("unroll") for (int qq = 0; qq < 4; ++qq)                          \
        _Pragma("unroll") for (int mt = 0; mt < 4; ++mt) {                    \
      sacc[qq][mt][0] = EXP2(sacc[qq][mt][0]);                                \
      sacc[qq][mt][1] = EXP2(sacc[qq][mt][1]);                                \
      sacc[qq][mt][2] = EXP2(sacc[qq][mt][2]);                                \
      sacc[qq][mt][3] = EXP2(sacc[qq][mt][3]);                                \
    }                                                                         \
    s16x8 pbh[4][2];                                                          \
    _Pragma("unroll") for (int qq = 0; qq < 4; ++qq)                          \
        _Pragma("unroll") for (int ks = 0; ks < 2; ++ks) {                    \
      i32x4 pw;                                                               \
      _Pragma("unroll") for (int d = 0; d < 4; ++d) {                         \
        const int mtd = 2 * ks + (d >> 1);                                    \
        const int j0 = (d & 1) * 2;                                           \
        pw[d] = pack_trunc(sacc[qq][mtd][j0], sacc[qq][mtd][j0 + 1]);         \
      }                                                                       \
      pbh[qq][ks] = __builtin_bit_cast(s16x8, pw);                            \
    }                                                                         \
    __builtin_amdgcn_s_setprio(1);                                            \
    _Pragma("unroll") for (int qq = 0; qq < 4; ++qq) {                        \
      lacc[qq] = __builtin_amdgcn_mfma_f32_16x16x32_bf16(                     \
          vones, pbh[qq][0], lacc[qq], 0, 0, 0);                              \
      lacc[qq] = __builtin_amdgcn_mfma_f32_16x16x32_bf16(                     \
          vones, pbh[qq][1], lacc[qq], 0, 0, 0);                              \
    }                                                                         \
    _Pragma("unroll") for (int mt = 0; mt < 4; ++mt) {                        \
      const int row = mt * 16 + col;                                          \
      const int sw = (row & 7) << 1;                                          \
      _Pragma("unroll") for (int ks = 0; ks < 2; ++ks) {                      \
        const int c0 = (8 * ks + 2 * g) ^ sw;                                 \
        const s16x8 vh = *(const s16x8*)&lds[grp][BUF][1][row * 64 + c0 * 4]; \
        _Pragma("unroll") for (int qq = 0; qq < 4; ++qq)                      \
            oacc[qq][mt] = __builtin_amdgcn_mfma_f32_16x16x32_bf16(           \
                vh, pbh[qq][ks], oacc[qq][mt], 0, 0, 0);                      \
      }                                                                       \
    }                                                                         \
    __builtin_amdgcn_s_setprio(0);                                            \
  }

  LOAD_TILE(64 * grp);
  WRITE_TILE(0);
  __syncthreads();

  for (int i = 0; i < 16; i += 2) {
    if (i + 1 < 16) LOAD_TILE(128 * (i + 1) + 64 * grp);
    COMPUTE(0);
    if (i + 1 < 16) WRITE_TILE(1);
    __syncthreads();
    if (i + 2 < 16) LOAD_TILE(128 * (i + 2) + 64 * grp);
    COMPUTE(1);
    if (i + 2 < 16) WRITE_TILE(0);
    __syncthreads();
  }

  // ---- linear merge: group 1 -> LDS, group 0 adds, normalizes, writes ----
  float* fbuf = (float*)&lds[0][0][0][0];
  if (grp == 1) {
#pragma unroll
    for (int qq = 0; qq < 4; ++qq) {
      Lsh[(w * 4 + qq) * 16 + col] = lacc[qq][0];
#pragma unroll
      for (int mt = 0; mt < 4; ++mt) {
        const int idx = ((w * 4 + qq) * 4 + mt) * 256 + lane * 4;
        *(float4*)&fbuf[idx] = make_float4(oacc[qq][mt][0], oacc[qq][mt][1],
                                           oacc[qq][mt][2], oacc[qq][mt][3]);
      }
    }
  }
  __syncthreads();
  if (grp == 0) {
    const int b = bh >> 4;
    const int h = bh & 15;
#pragma unroll
    for (int qq = 0; qq < 4; ++qq) {
      const float l1 = Lsh[(w * 4 + qq) * 16 + col];
      const float inv = 1.0f / (lacc[qq][0] + l1);
      const int q = q0 + w * 64 + qq * 16 + col;
      const size_t rb = ((size_t)b * SS + q) * DMODEL + h * DKK;
#pragma unroll
      for (int mt = 0; mt < 4; ++mt) {
        const int idx = ((w * 4 + qq) * 4 + mt) * 256 + lane * 4;
        const float4 o1 = *(const float4*)&fbuf[idx];
        short4 h4, l4;
        split1((oacc[qq][mt][0] + o1.x) * inv, h4.x, l4.x);
        split1((oacc[qq][mt][1] + o1.y) * inv, h4.y, l4.y);
        split1((oacc[qq][mt][2] + o1.z) * inv, h4.z, l4.z);
        split1((oacc[qq][mt][3] + o1.w) * inv, h4.w, l4.w);
        *(short4*)&AOh[rb + mt * 16 + g * 4] = h4;
        *(short4*)&AOl[rb + mt * 16 + g * 4] = l4;
      }
    }
  }
#undef LOAD_TILE
#undef WRITE_TILE
#undef COMPUTE
}

extern "C" void kernel_launch(void* const* d_in, const int* in_sizes, int n_in,
                              void* d_out, int out_size, void* d_ws,
                              size_t ws_size, hipStream_t stream) {
  const float* query = (const float*)d_in[0];
  const float* key   = (const float*)d_in[1];
  const float* value = (const float*)d_in[2];
  const float* w_q   = (const float*)d_in[3];
  const float* w_k   = (const float*)d_in[4];
  const float* w_v   = (const float*)d_in[5];
  const float* w_o   = (const float*)d_in[6];
  const float* b_o   = (const float*)d_in[7];
  float* out = (float*)d_out;

  const size_t per = (size_t)BB * NHEAD * SS * DKK;   // 4,194,304 elements
  const size_t wsz = (size_t)DMODEL * DMODEL;
  short* Qbh = (short*)d_ws;     // bf16 Q (pre-scaled)
  short* Kbh = Qbh + per;        // bf16 K
  short* Vth = Kbh + per;        // bf16 V^T
  short* AOh = Vth + per;        // attention out hi
  short* AOl = AOh + per;        // attention out lo
  short* WhiA = AOl + per;       // 4 weights hi (q,k,v,o)
  short* WloA = WhiA + 4 * wsz;  // 2 compact lo slots (v, o)

  const float QSCALE = 0.125f * 1.4426950408889634f;  // 1/sqrt(64)*log2(e)
  dim3 blk(256);

  prep_all<<<4096, blk, 0, stream>>>(w_q, w_k, w_v, w_o, WhiA, WloA);

  dim3 gqkv(DMODEL / 128, (BB * SS) / 128, 3);  // (8, 32, 3) = 768 blocks
  gemm_qkv<<<gqkv, blk, 0, stream>>>(query, key, value, WhiA, WloA, QSCALE,
                                     Qbh, Kbh, Vth);

  dim3 gattn(SS / 256, BB * NHEAD);  // (8, 32) = 256 blocks, 512 thr
  attn_mfma<<<gattn, dim3(512), 0, stream>>>(Qbh, Kbh, Vth, AOh, AOl);

  dim3 ggemm(DMODEL / 64, (BB * SS) / 128);  // (16, 32)
  gemm_split_o<<<ggemm, blk, 0, stream>>>(AOh, AOl, WhiA + 3 * wsz,
                                          WloA + 1 * wsz, b_o, out);
}